// Round 5
// baseline (138.862 us; speedup 1.0000x reference)
//
#include <hip/hip_runtime.h>
#include <hip/hip_bf16.h>

// Conv2dWithLoRA: out = conv3x3(x, W_eff) + b, where W_eff = W + 2.0 * B@A.
// LoRA folded into weights -> single implicit-GEMM conv, bf16 MFMA, fp32 accum.
// M = 16*64*64 = 65536 pixels, N = 256 outs, K = 128*9 = 1152.
// R3: 256x256 tile, 8 waves, depth-1 double buffer -> MfmaUtil 32%.
// R4/R5: BK=32 quad-buffer depth-3 pipeline -> neutral (4-way bank conflict).
// R6: conflict-free swizzle (slot = c ^ ((r>>1)&3)) + swapped-operand epilogue
//     (dwordx4 stores) -> conflicts 0 but STILL neutral: reads and MFMAs are
//     serial (lockstep convoy: all waves read, then all MFMA). 57% idle issue.
// R7 (this round): m201-style fine phase-split (T3+T4+T5 full stack):
//   - each chunk = 2 phases of 16 MFMA; per phase {ds_read subtile ∥ STAGE}
//     -> s_barrier -> lgkmcnt(0) -> setprio(1) MFMA x16 setprio(0).
//   - next phase's ds_reads issue while matrix pipe drains the cluster
//     (s_barrier doesn't wait MFMA completion) -> LDS/matrix pipes overlap.
//   - counted vmcnt(8) once per chunk (depth-3 prefetch, never drains to 0).
//   - sched_barrier(0) pins phase boundaries (compiler must not sink
//     register-only MFMAs across s_barrier and re-merge clusters).

#define CIN   128
#define COUT  256
#define NBAT  16
#define HPAD  66
#define WPAD  66

typedef __bf16 bf16x8 __attribute__((ext_vector_type(8)));
typedef float f32x4 __attribute__((ext_vector_type(4)));

#define XPAD_ELEMS ((size_t)NBAT * HPAD * WPAD * CIN)   // 8,921,088
#define XPAD_BYTES (XPAD_ELEMS * 2)                      // 17,842,176
#define WT_ELEMS   ((size_t)9 * COUT * CIN)              // 294,912
#define WS_NEED    (XPAD_BYTES + WT_ELEMS * 2)

typedef __attribute__((address_space(1))) void gvoid;
typedef __attribute__((address_space(3))) void lvoid;

__device__ __forceinline__ void load_lds16(const void* g, void* l) {
    // async global->LDS, 16B per lane; LDS dest = wave-uniform base + lane*16
    __builtin_amdgcn_global_load_lds((gvoid*)g, (lvoid*)l, 16, 0, 0);
}

// ---------------------------------------------------------------------------
// Fused pre-kernel: blocks [0,1024) = pad_x, blocks [1024,1152) = prep_w.
__global__ void pad_prep(const float* __restrict__ x, __bf16* __restrict__ xpad,
                         const float* __restrict__ W, const float* __restrict__ lA,
                         const float* __restrict__ lB, __hip_bfloat16* __restrict__ Wt) {
    __shared__ float tile[128][66];
    const int t = threadIdx.x;

    if (blockIdx.x >= 1024) {
        // ---- prep_w: 128 blocks, each thread owns one (o,c), loops 9 taps
        const int idx = (blockIdx.x - 1024) * 256 + t;   // o*128 + c
        const int c = idx & 127;
        const int o = idx >> 7;
        float lb[8];
#pragma unroll
        for (int r = 0; r < 8; ++r) lb[r] = lB[o * 8 + r];
#pragma unroll
        for (int tap = 0; tap < 9; ++tap) {
            float acc = W[(o * 128 + c) * 9 + tap];
            float s = 0.f;
#pragma unroll
            for (int r = 0; r < 8; ++r)
                s += lb[r] * lA[r * 1152 + c * 9 + tap];
            Wt[tap * 32768 + idx] = __float2bfloat16(acc + 2.0f * s);
        }
        return;
    }

    // ---- pad_x: NCHW fp32 -> NHWC bf16 with +1 zero halo
    const int n = blockIdx.x >> 6;
    const int h = blockIdx.x & 63;
    const float* src = x + (size_t)n * 128 * 4096 + (size_t)h * 64;
#pragma unroll
    for (int i = 0; i < 8; ++i) {                      // 2048 float4 total
        int g  = i * 256 + t;
        int c  = g >> 4;
        int w4 = (g & 15) * 4;
        const float4 v = *reinterpret_cast<const float4*>(src + (size_t)c * 4096 + w4);
        const int wb = w4 ^ (((c >> 3) & 7) << 2);     // swizzle (bits 2..4)
        tile[c][wb + 0] = v.x; tile[c][wb + 1] = v.y;
        tile[c][wb + 2] = v.z; tile[c][wb + 3] = v.w;
    }
    __syncthreads();
    __bf16* dst = xpad + ((size_t)(n * 66 + h + 1) * 66 + 1) * 128;
#pragma unroll
    for (int i = 0; i < 4; ++i) {                      // 64w x 128c bf16 = 16KB
        int g  = i * 256 + t;
        int w  = g >> 4;
        int c0 = (g & 15) * 8;
        const int swr = ((c0 >> 3) & 7) << 2;          // (c0+j)>>3 == c0>>3, j<8
        bf16x8 v;
#pragma unroll
        for (int j = 0; j < 8; ++j) v[j] = (__bf16)tile[c0 + j][w ^ swr];
        *reinterpret_cast<bf16x8*>(dst + (size_t)w * 128 + c0) = v;
    }
    // halo: left/right pixel of this padded row
    bf16x8 z = {};
    __bf16* rowbase = xpad + (size_t)(n * 66 + h + 1) * 66 * 128;
    if (t < 32) {
        int ww = (t < 16) ? 0 : 65;
        int c0 = (t & 15) * 8;
        *reinterpret_cast<bf16x8*>(rowbase + (size_t)ww * 128 + c0) = z;
    }
    // top/bottom halo rows (full 66 px)
    if (h == 0 || h == 63) {
        __bf16* hrow = xpad + (size_t)(n * 66 + (h == 0 ? 0 : 65)) * 66 * 128;
        for (int i = t; i < 66 * 16; i += 256)
            *reinterpret_cast<bf16x8*>(hrow + (size_t)i * 8) = z;
    }
}

// ---------------------------------------------------------------------------
// Main kernel: implicit-GEMM conv. Tile 256(o) x 256(pix), BK=32, 8 waves,
// quad-buffered depth-3 pipeline, 2-phase fine interleave per chunk.
//
// LDS map (bf16 elems): A bufs 0..3 at [0 + q*8192), B bufs at [32768 + q*8192)
// where q = chunk&3. Chunk u (0..35): tap = u>>2, cb = u&3 (32-ch slice).
//
// Swizzle (conflict-free for 64B rows): physical 16B slot of logical chunk c
// in row r is  s = c ^ ((r>>1)&3).  Bank-quad position = 4*(r&1) + s covers
// all 8 positions over any 8 consecutive rows -> 2-way aliasing only.
// Inverse perm pre-applied on the per-lane GLOBAL address (lswz); LDS dest
// stays linear (global_load_lds requirement, rule #21).
//
// Chunk t body:
//   vmcnt(8); SBAR; STAGE(t+3); read bfr[0..3]+af[0..3]; lgkm0;
//   prio1 MFMA(oi 0..3) prio0; SBAR; read af[4..7]; lgkm0;
//   prio1 MFMA(oi 4..7) prio0;
// Safety: STAGE(t+3) targets buf (t-1)&3; every wave's reads of chunk t-1
// completed before its MFMA(t-1) (lgkmcnt), which precedes the chunk-t SBAR.
__global__ void __launch_bounds__(512, 2) conv_mfma(
    const __bf16* __restrict__ xpad, const __bf16* __restrict__ Wt,
    const float* __restrict__ bias, float* __restrict__ out) {
    __shared__ __align__(16) __bf16 lds[65536];        // 128 KiB

    const int tid  = threadIdx.x;
    const int wv   = tid >> 6;                         // 0..7
    const int lane = tid & 63;

    const int n  = blockIdx.x >> 4;                    // 16 tiles per image
    const int h0 = (blockIdx.x & 15) << 2;             // 4 output rows per tile

    // ---- staging addresses --------------------------------------------------
    // One stage instr covers 16 rows x 32 elems (64 lanes x 16B = 1 KB).
    // lane l: row = base + (l>>2), physical slot l&3 receives logical chunk
    // (l&3) ^ ((row>>1)&3)  (row bases are multiples of 16).
    const int lrow = lane >> 2;                                    // 0..15
    const int lswz = (((lane & 3) ^ ((lane >> 3) & 3)) << 3);      // elems
    const __bf16* aG[2];
    const __bf16* bG[2];
#pragma unroll
    for (int j = 0; j < 2; ++j) {
        const int r0 = j * 128 + wv * 16;              // first row of this instr
        aG[j] = Wt + (r0 + lrow) * 128 + lswz;
        // pixel p = r0 + lrow; within one instr p>>6 is constant (r0 mult of 16)
        bG[j] = xpad + (((size_t)(n * 66 + h0 + (r0 >> 6)) * 66 + (r0 & 63) + lrow) * 128) + lswz;
    }

    // ---- fragment-read addresses -------------------------------------------
    const int wo   = (wv >> 2) << 7;                   // o offset: 0 / 128
    const int wpix = (wv & 3) << 6;                    // pix offset: 0/64/128/192
    const int fr   = lane & 15;
    // logical k-chunk = lane>>4; physical = logical ^ ((row>>1)&3), row%16 = fr
    const int fphys = (((lane >> 4) ^ ((lane >> 1) & 3)) << 3);
    const int a_rd = (wo + fr) * 32 + fphys;           // + oi*512 + buf
    const int b_rd = (wpix + fr) * 32 + fphys;         // + pi*512 + buf

    f32x4 acc[4][8] = {};                              // [pixel tile][o tile]

#define STAGE(u) do {                                                          \
        const int tap_ = (u) >> 2, cb_ = (u) & 3;                              \
        const int kh_ = (tap_ >= 6) ? 2 : (tap_ >= 3 ? 1 : 0);                 \
        const int kw_ = tap_ - kh_ * 3;                                        \
        const int ao_ = tap_ * 32768 + cb_ * 32;                               \
        const int bo_ = (kh_ * 66 + kw_) * 128 + cb_ * 32;                     \
        const int lb_ = ((u) & 3) * 8192;                                      \
        load_lds16(aG[0] + ao_, lds + lb_ + (wv * 16) * 32);                   \
        load_lds16(aG[1] + ao_, lds + lb_ + (128 + wv * 16) * 32);             \
        load_lds16(bG[0] + bo_, lds + 32768 + lb_ + (wv * 16) * 32);           \
        load_lds16(bG[1] + bo_, lds + 32768 + lb_ + (128 + wv * 16) * 32);     \
    } while (0)

    // Two-phase compute: 16 MFMA per phase, reads of next phase overlap the
    // matrix-pipe drain of the previous cluster.
#define COMPUTE2(t) do {                                                       \
        const int lb_ = ((t) & 3) * 8192;                                      \
        const __bf16* Ab = lds + lb_ + a_rd;                                   \
        const __bf16* Bb = lds + 32768 + lb_ + b_rd;                           \
        bf16x8 bfr[4], af[4], ag[4];                                           \
        _Pragma("unroll")                                                      \
        for (int pi = 0; pi < 4; ++pi)                                         \
            bfr[pi] = *reinterpret_cast<const bf16x8*>(Bb + pi * 512);         \
        _Pragma("unroll")                                                      \
        for (int oi = 0; oi < 4; ++oi)                                         \
            af[oi] = *reinterpret_cast<const bf16x8*>(Ab + oi * 512);          \
        asm volatile("s_waitcnt lgkmcnt(0)" ::: "memory");                     \
        __builtin_amdgcn_sched_barrier(0);                                     \
        __builtin_amdgcn_s_setprio(1);                                         \
        _Pragma("unroll")                                                      \
        for (int pi = 0; pi < 4; ++pi)                                         \
            _Pragma("unroll")                                                  \
            for (int oi = 0; oi < 4; ++oi)                                     \
                acc[pi][oi] = __builtin_amdgcn_mfma_f32_16x16x32_bf16(         \
                    bfr[pi], af[oi], acc[pi][oi], 0, 0, 0);                    \
        __builtin_amdgcn_s_setprio(0);                                         \
        __builtin_amdgcn_sched_barrier(0);                                     \
        __builtin_amdgcn_s_barrier();                  /* phase boundary */    \
        __builtin_amdgcn_sched_barrier(0);                                     \
        _Pragma("unroll")                                                      \
        for (int oi = 0; oi < 4; ++oi)                                         \
            ag[oi] = *reinterpret_cast<const bf16x8*>(Ab + (4 + oi) * 512);    \
        asm volatile("s_waitcnt lgkmcnt(0)" ::: "memory");                     \
        __builtin_amdgcn_sched_barrier(0);                                     \
        __builtin_amdgcn_s_setprio(1);                                         \
        _Pragma("unroll")                                                      \
        for (int pi = 0; pi < 4; ++pi)                                         \
            _Pragma("unroll")                                                  \
            for (int oi = 0; oi < 4; ++oi)                                     \
                acc[pi][4 + oi] = __builtin_amdgcn_mfma_f32_16x16x32_bf16(     \
                    bfr[pi], ag[oi], acc[pi][4 + oi], 0, 0, 0);                \
        __builtin_amdgcn_s_setprio(0);                                         \
        __builtin_amdgcn_sched_barrier(0);                                     \
    } while (0)

    // prologue: prefetch chunks 0,1,2 (12 VMEM instrs in flight)
    STAGE(0); STAGE(1); STAGE(2);

    for (int t = 0; t < 33; ++t) {
        // chunk t's 4 loads done; t+1,t+2 (8 instrs) stay in flight
        asm volatile("s_waitcnt vmcnt(8)" ::: "memory");
        __builtin_amdgcn_sched_barrier(0);
        __builtin_amdgcn_s_barrier();                  // all waves: chunk t visible
        __builtin_amdgcn_sched_barrier(0);
        STAGE(t + 3);
        COMPUTE2(t);
    }
    // t = 33: outstanding = chunks 33,34,35 (12 instrs)
    asm volatile("s_waitcnt vmcnt(8)" ::: "memory");
    __builtin_amdgcn_sched_barrier(0);
    __builtin_amdgcn_s_barrier();
    __builtin_amdgcn_sched_barrier(0);
    COMPUTE2(33);
    // t = 34: outstanding = chunks 34,35 (8 instrs)
    asm volatile("s_waitcnt vmcnt(4)" ::: "memory");
    __builtin_amdgcn_sched_barrier(0);
    __builtin_amdgcn_s_barrier();
    __builtin_amdgcn_sched_barrier(0);
    COMPUTE2(34);
    // t = 35: outstanding = chunk 35 (4 instrs)
    asm volatile("s_waitcnt vmcnt(0)" ::: "memory");
    __builtin_amdgcn_sched_barrier(0);
    __builtin_amdgcn_s_barrier();
    __builtin_amdgcn_sched_barrier(0);
    COMPUTE2(35);

#undef STAGE
#undef COMPUTE2

    // epilogue (swapped D): row=(lane>>4)*4+j = pixel, col=lane&15 = o.
    // Lane's 4 acc components = 4 consecutive w -> dwordx4 stores.
    const int col = lane & 15;
    const int q4  = (lane >> 4) << 2;                  // pixel sub-offset
    const int h   = h0 + (wpix >> 6);                  // wpix multiple of 64
    float bo[8];
#pragma unroll
    for (int oi = 0; oi < 8; ++oi) bo[oi] = bias[wo + oi * 16 + col];
#pragma unroll
    for (int pi = 0; pi < 4; ++pi) {
        const int w0 = pi * 16 + q4;                   // wpix&63 == 0
#pragma unroll
        for (int oi = 0; oi < 8; ++oi) {
            const int o = wo + oi * 16 + col;
            f32x4 v;
#pragma unroll
            for (int j = 0; j < 4; ++j) v[j] = acc[pi][oi][j] + bo[oi];
            *reinterpret_cast<f32x4*>(out + (((size_t)n * 256 + o) * 64 + h) * 64 + w0) = v;
        }
    }
}

// ---------------------------------------------------------------------------
// Fallback (only if workspace too small): naive fp32, correct but slow.
__global__ void conv_naive(const float* __restrict__ x, const float* __restrict__ W,
                           const float* __restrict__ b, const float* __restrict__ lA,
                           const float* __restrict__ lB, float* __restrict__ out) {
    int idx = blockIdx.x * 256 + threadIdx.x;          // ((n*256+o)*64+h)*64+w
    int w = idx & 63, h = (idx >> 6) & 63, o = (idx >> 12) & 255, n = idx >> 20;
    float acc = b[o];
    float hr[8] = {0, 0, 0, 0, 0, 0, 0, 0};
    for (int c = 0; c < 128; ++c)
        for (int kh = 0; kh < 3; ++kh) {
            int hy = h + kh - 1;
            if (hy < 0 || hy > 63) continue;
            for (int kw = 0; kw < 3; ++kw) {
                int wx = w + kw - 1;
                if (wx < 0 || wx > 63) continue;
                float xv = x[((n * 128 + c) * 64 + hy) * 64 + wx];
                int ka = c * 9 + kh * 3 + kw;
                acc += W[(o * 128 + c) * 9 + kh * 3 + kw] * xv;
#pragma unroll
                for (int r = 0; r < 8; ++r) hr[r] += lA[r * 1152 + ka] * xv;
            }
        }
    float ls = 0.f;
#pragma unroll
    for (int r = 0; r < 8; ++r) ls += lB[o * 8 + r] * hr[r];
    out[idx] = acc + 2.0f * ls;
}

// ---------------------------------------------------------------------------
extern "C" void kernel_launch(void* const* d_in, const int* in_sizes, int n_in,
                              void* d_out, int out_size, void* d_ws, size_t ws_size,
                              hipStream_t stream) {
    const float* x  = (const float*)d_in[0];
    const float* W  = (const float*)d_in[1];
    const float* b  = (const float*)d_in[2];
    const float* lA = (const float*)d_in[3];
    const float* lB = (const float*)d_in[4];
    float* out = (float*)d_out;

    if (ws_size < WS_NEED) {
        conv_naive<<<out_size / 256, 256, 0, stream>>>(x, W, b, lA, lB, out);
        return;
    }

    __bf16* xpad = (__bf16*)d_ws;
    __hip_bfloat16* Wt = (__hip_bfloat16*)((char*)d_ws + XPAD_BYTES);

    pad_prep<<<1024 + 128, 256, 0, stream>>>(x, xpad, W, lA, lB, Wt);
    conv_mfma<<<256, 512, 0, stream>>>(xpad, (const __bf16*)Wt, b, out);
}

// Round 6
// 136.257 us; speedup vs baseline: 1.0191x; 1.0191x over previous
//
#include <hip/hip_runtime.h>
#include <hip/hip_bf16.h>

// Conv2dWithLoRA: out = conv3x3(x, W_eff) + b, where W_eff = W + 2.0 * B@A.
// LoRA folded into weights -> single implicit-GEMM conv, bf16 MFMA, fp32 accum.
// M = 16*64*64 = 65536 pixels, N = 256 outs, K = 128*9 = 1152 (36 chunks of 32).
// R3..R7 history: 3 different schedules (depth-1 dbuf / depth-3 quad-buffer /
//   2-phase split) ALL land at 29-32% MfmaUtil -> schedule is not the lever.
//   Invariant cost: LDS port serialization (96 ds_read_b128 + 32KB writes per
//   chunk per CU ~ 1400 cyc, serial with 1240 cyc MFMA under barrier convoy).
// R8 (this round): WEIGHTS OUT OF LDS.
//   - weight fragments loaded global->VGPR via asm global_load_dwordx4 from a
//     fragment-contiguous layout (prep_w emits Wt[(tap*4+cb)*16+otile][lane][8];
//     each load = 64 lanes x contiguous 16B = 1KB, perfectly coalesced, L2-hot).
//   - ds_reads/wave/chunk: 12 -> 4 (pixels only); LDS 128 -> 64 KB; A-staging
//     instrs gone. Critical path ~= MFMA.
//   - pipeline: B 4-buffer stage depth-2, weights depth-1 in named wA/wB reg
//     sets (static indexing only), uniform vmcnt(2)/chunk, 1 barrier/chunk.
//     Accounting: per iter issue = [8 wloads(t+1), 2 stages(t+2)]; at iter-t
//     top vmcnt(2) retires w(t)+sB(t), leaves sB(t+1) in flight. Tail: t=34
//     issues w35 only; t=35 waits vmcnt(0).

#define CIN   128
#define COUT  256
#define NBAT  16
#define HPAD  66
#define WPAD  66

typedef __bf16 bf16x8 __attribute__((ext_vector_type(8)));
typedef float f32x4 __attribute__((ext_vector_type(4)));

#define XPAD_ELEMS ((size_t)NBAT * HPAD * WPAD * CIN)   // 8,921,088
#define XPAD_BYTES (XPAD_ELEMS * 2)                      // 17,842,176
#define WT_ELEMS   ((size_t)9 * COUT * CIN)              // 294,912
#define WS_NEED    (XPAD_BYTES + WT_ELEMS * 2)

typedef __attribute__((address_space(1))) void gvoid;
typedef __attribute__((address_space(3))) void lvoid;

__device__ __forceinline__ void load_lds16(const void* g, void* l) {
    // async global->LDS, 16B per lane; LDS dest = wave-uniform base + lane*16
    __builtin_amdgcn_global_load_lds((gvoid*)g, (lvoid*)l, 16, 0, 0);
}

// ---------------------------------------------------------------------------
// Fused pre-kernel: blocks [0,1024) = pad_x, blocks [1024,1152) = prep_w.
// prep_w writes the FRAGMENT-CONTIGUOUS weight layout:
//   Wt[(((tap*4 + cb)*16 + otile)*64 + lane)*8 + j]
//   where o = otile*16 + (lane&15), c = cb*32 + (lane>>4)*8 + j.
// A conv wave then loads fragment (tap,cb,otile) as one contiguous 1KB
// global_load_dwordx4 (lane l -> base + l*16B), no LDS, no swizzle.
__global__ void pad_prep(const float* __restrict__ x, __bf16* __restrict__ xpad,
                         const float* __restrict__ W, const float* __restrict__ lA,
                         const float* __restrict__ lB, __hip_bfloat16* __restrict__ Wt) {
    __shared__ float tile[128][66];
    const int t = threadIdx.x;

    if (blockIdx.x >= 1024) {
        // ---- prep_w: 128 blocks, each thread owns one (o,c), loops 9 taps
        const int idx = (blockIdx.x - 1024) * 256 + t;   // o*128 + c
        const int c = idx & 127;
        const int o = idx >> 7;
        const int fr    = o & 15;
        const int otile = o >> 4;
        const int cb    = c >> 5;
        const int kc    = (c >> 3) & 3;
        const int j     = c & 7;
        const int lane  = kc * 16 + fr;
        float lb[8];
#pragma unroll
        for (int r = 0; r < 8; ++r) lb[r] = lB[o * 8 + r];
#pragma unroll
        for (int tap = 0; tap < 9; ++tap) {
            float acc = W[(o * 128 + c) * 9 + tap];
            float s = 0.f;
#pragma unroll
            for (int r = 0; r < 8; ++r)
                s += lb[r] * lA[r * 1152 + c * 9 + tap];
            const size_t widx = (((size_t)(tap * 4 + cb) * 16 + otile) * 64 + lane) * 8 + j;
            Wt[widx] = __float2bfloat16(acc + 2.0f * s);
        }
        return;
    }

    // ---- pad_x: NCHW fp32 -> NHWC bf16 with +1 zero halo
    const int n = blockIdx.x >> 6;
    const int h = blockIdx.x & 63;
    const float* src = x + (size_t)n * 128 * 4096 + (size_t)h * 64;
#pragma unroll
    for (int i = 0; i < 8; ++i) {                      // 2048 float4 total
        int g  = i * 256 + t;
        int c  = g >> 4;
        int w4 = (g & 15) * 4;
        const float4 v = *reinterpret_cast<const float4*>(src + (size_t)c * 4096 + w4);
        const int wb = w4 ^ (((c >> 3) & 7) << 2);     // swizzle (bits 2..4)
        tile[c][wb + 0] = v.x; tile[c][wb + 1] = v.y;
        tile[c][wb + 2] = v.z; tile[c][wb + 3] = v.w;
    }
    __syncthreads();
    __bf16* dst = xpad + ((size_t)(n * 66 + h + 1) * 66 + 1) * 128;
#pragma unroll
    for (int i = 0; i < 4; ++i) {                      // 64w x 128c bf16 = 16KB
        int g  = i * 256 + t;
        int w  = g >> 4;
        int c0 = (g & 15) * 8;
        const int swr = ((c0 >> 3) & 7) << 2;          // (c0+j)>>3 == c0>>3, j<8
        bf16x8 v;
#pragma unroll
        for (int j = 0; j < 8; ++j) v[j] = (__bf16)tile[c0 + j][w ^ swr];
        *reinterpret_cast<bf16x8*>(dst + (size_t)w * 128 + c0) = v;
    }
    // halo: left/right pixel of this padded row
    bf16x8 z = {};
    __bf16* rowbase = xpad + (size_t)(n * 66 + h + 1) * 66 * 128;
    if (t < 32) {
        int ww = (t < 16) ? 0 : 65;
        int c0 = (t & 15) * 8;
        *reinterpret_cast<bf16x8*>(rowbase + (size_t)ww * 128 + c0) = z;
    }
    // top/bottom halo rows (full 66 px)
    if (h == 0 || h == 63) {
        __bf16* hrow = xpad + (size_t)(n * 66 + (h == 0 ? 0 : 65)) * 66 * 128;
        for (int i = t; i < 66 * 16; i += 256)
            *reinterpret_cast<bf16x8*>(hrow + (size_t)i * 8) = z;
    }
}

// ---------------------------------------------------------------------------
// Main kernel. Tile 256(o) x 256(pix), BK=32, 8 waves (2 o-halves x 4 pix-
// quarters), per-wave output 64 pix x 128 o.
// LDS: B (pixels) only, 4 buffers x 16KB = 64 KB, buf = chunk&3.
// Weights: depth-1 prefetch into named reg sets wA/wB (8 x f32x4 each).
// Swizzle (B only, 64B rows): slot = c ^ ((r>>1)&3); inverse pre-applied on
// the per-lane GLOBAL address, LDS dest linear (rule #21).
__global__ void __launch_bounds__(512, 2) conv_mfma(
    const __bf16* __restrict__ xpad, const __bf16* __restrict__ Wt,
    const float* __restrict__ bias, float* __restrict__ out) {
    __shared__ __align__(16) __bf16 lds[32768];        // 64 KiB

    const int tid  = threadIdx.x;
    const int wv   = tid >> 6;                         // 0..7
    const int lane = tid & 63;

    const int n  = blockIdx.x >> 4;                    // 16 tiles per image
    const int h0 = (blockIdx.x & 15) << 2;             // 4 output rows per tile

    // ---- B staging addresses (pixels) --------------------------------------
    const int lrow = lane >> 2;                                    // 0..15
    const int lswz = (((lane & 3) ^ ((lane >> 3) & 3)) << 3);      // elems
    const __bf16* bG[2];
#pragma unroll
    for (int j = 0; j < 2; ++j) {
        const int r0 = j * 128 + wv * 16;              // first pixel row
        bG[j] = xpad + (((size_t)(n * 66 + h0 + (r0 >> 6)) * 66 + (r0 & 63) + lrow) * 128) + lswz;
    }

    // ---- per-wave geometry --------------------------------------------------
    const int wo   = (wv >> 2) << 7;                   // o offset: 0 / 128
    const int wot  = (wv >> 2) << 3;                   // o-tile base: 0 / 8
    const int wpix = (wv & 3) << 6;                    // pix offset: 0/64/128/192
    const int fr   = lane & 15;
    const int fphys = (((lane >> 4) ^ ((lane >> 1) & 3)) << 3);
    const int b_rd = (wpix + fr) * 32 + fphys;         // + pi*512 + buf

    // weight fragment base: lane-contiguous layout
    const __bf16* wG = Wt + (size_t)wot * 512 + lane * 8;

    f32x4 acc[4][8] = {};                              // [pix tile][o tile]
    f32x4 wA[8], wB[8];                                // weight frags (named!)

#define WL(dst, ptr, imm)                                                      \
    asm volatile("global_load_dwordx4 %0, %1, off offset:" #imm                \
                 : "=&v"(dst) : "v"(ptr) : "memory")

#define WLOADS(WN, u) do {                                                     \
        const __bf16* wp0_ = wG + (size_t)(u) * 8192;                          \
        const __bf16* wp1_ = wp0_ + 2048;                                      \
        WL(WN[0], wp0_, 0);    WL(WN[1], wp0_, 1024);                          \
        WL(WN[2], wp0_, 2048); WL(WN[3], wp0_, 3072);                          \
        WL(WN[4], wp1_, 0);    WL(WN[5], wp1_, 1024);                          \
        WL(WN[6], wp1_, 2048); WL(WN[7], wp1_, 3072);                          \
    } while (0)

#define STAGE(u) do {                                                          \
        const int u_ = (u);                                                    \
        const int tap_ = u_ >> 2, cb_ = u_ & 3;                                \
        const int kh_ = (tap_ >= 6) ? 2 : (tap_ >= 3 ? 1 : 0);                 \
        const int kw_ = tap_ - kh_ * 3;                                        \
        const int bo_ = (kh_ * 66 + kw_) * 128 + cb_ * 32;                     \
        const int lb_ = (u_ & 3) * 8192;                                       \
        load_lds16(bG[0] + bo_, lds + lb_ + (wv * 16) * 32);                   \
        load_lds16(bG[1] + bo_, lds + lb_ + (128 + wv * 16) * 32);             \
    } while (0)

#define COMPUTE(t_, WC) do {                                                   \
        const __bf16* Bb = lds + ((t_) & 3) * 8192 + b_rd;                     \
        bf16x8 bfr[4];                                                         \
        _Pragma("unroll")                                                      \
        for (int pi = 0; pi < 4; ++pi)                                         \
            bfr[pi] = *reinterpret_cast<const bf16x8*>(Bb + pi * 512);         \
        __builtin_amdgcn_s_setprio(1);                                         \
        _Pragma("unroll")                                                      \
        for (int pi = 0; pi < 4; ++pi)                                         \
            _Pragma("unroll")                                                  \
            for (int oi = 0; oi < 8; ++oi)                                     \
                acc[pi][oi] = __builtin_amdgcn_mfma_f32_16x16x32_bf16(         \
                    bfr[pi], __builtin_bit_cast(bf16x8, WC[oi]),               \
                    acc[pi][oi], 0, 0, 0);                                     \
        __builtin_amdgcn_s_setprio(0);                                         \
    } while (0)

    // iter body: vmcnt(2) retires w(t) + sB(t), leaves sB(t+1) in flight;
    // barrier makes chunk-t staging visible to all waves; then issue
    // w(t+1) -> WN and sB(t+2); compute chunk t from WC + LDS buf t&3.
#define BODY(t_, WC, WN) do {                                                  \
        asm volatile("s_waitcnt vmcnt(2)" ::: "memory");                       \
        __builtin_amdgcn_sched_barrier(0);                                     \
        __builtin_amdgcn_s_barrier();                                          \
        __builtin_amdgcn_sched_barrier(0);                                     \
        WLOADS(WN, (t_) + 1);                                                  \
        __builtin_amdgcn_sched_barrier(0);                                     \
        STAGE((t_) + 2);                                                       \
        __builtin_amdgcn_sched_barrier(0);                                     \
        COMPUTE(t_, WC);                                                       \
    } while (0)

    // prologue: w0 -> wA, then stage chunks 0,1 (issue order matters: vmcnt
    // counting assumes [w0(8), sB0(2), sB1(2)] = 12 outstanding).
    WLOADS(wA, 0);
    __builtin_amdgcn_sched_barrier(0);
    STAGE(0);
    STAGE(1);
    __builtin_amdgcn_sched_barrier(0);

    for (int tt = 0; tt < 17; ++tt) {                  // chunks 0..33
        BODY(2 * tt,     wA, wB);
        BODY(2 * tt + 1, wB, wA);
    }
    // t = 34: issue w35 only (no stage 36)
    asm volatile("s_waitcnt vmcnt(2)" ::: "memory");
    __builtin_amdgcn_sched_barrier(0);
    __builtin_amdgcn_s_barrier();
    __builtin_amdgcn_sched_barrier(0);
    WLOADS(wB, 35);
    __builtin_amdgcn_sched_barrier(0);
    COMPUTE(34, wA);
    // t = 35: drain everything (sB35 + w35)
    asm volatile("s_waitcnt vmcnt(0)" ::: "memory");
    __builtin_amdgcn_sched_barrier(0);
    __builtin_amdgcn_s_barrier();
    __builtin_amdgcn_sched_barrier(0);
    COMPUTE(35, wB);

#undef BODY
#undef COMPUTE
#undef STAGE
#undef WLOADS
#undef WL

    // epilogue (swapped D): row=(lane>>4)*4+j = pixel, col=lane&15 = o.
    // Lane's 4 acc components = 4 consecutive w -> dwordx4 stores.
    const int col = lane & 15;
    const int q4  = (lane >> 4) << 2;                  // pixel sub-offset
    const int h   = h0 + (wpix >> 6);                  // wpix multiple of 64
    float bo[8];
#pragma unroll
    for (int oi = 0; oi < 8; ++oi) bo[oi] = bias[wo + oi * 16 + col];
#pragma unroll
    for (int pi = 0; pi < 4; ++pi) {
        const int w0 = pi * 16 + q4;                   // wpix&63 == 0
#pragma unroll
        for (int oi = 0; oi < 8; ++oi) {
            const int o = wo + oi * 16 + col;
            f32x4 v;
#pragma unroll
            for (int j = 0; j < 4; ++j) v[j] = acc[pi][oi][j] + bo[oi];
            *reinterpret_cast<f32x4*>(out + (((size_t)n * 256 + o) * 64 + h) * 64 + w0) = v;
        }
    }
}

// ---------------------------------------------------------------------------
// Fallback (only if workspace too small): naive fp32, correct but slow.
__global__ void conv_naive(const float* __restrict__ x, const float* __restrict__ W,
                           const float* __restrict__ b, const float* __restrict__ lA,
                           const float* __restrict__ lB, float* __restrict__ out) {
    int idx = blockIdx.x * 256 + threadIdx.x;          // ((n*256+o)*64+h)*64+w
    int w = idx & 63, h = (idx >> 6) & 63, o = (idx >> 12) & 255, n = idx >> 20;
    float acc = b[o];
    float hr[8] = {0, 0, 0, 0, 0, 0, 0, 0};
    for (int c = 0; c < 128; ++c)
        for (int kh = 0; kh < 3; ++kh) {
            int hy = h + kh - 1;
            if (hy < 0 || hy > 63) continue;
            for (int kw = 0; kw < 3; ++kw) {
                int wx = w + kw - 1;
                if (wx < 0 || wx > 63) continue;
                float xv = x[((n * 128 + c) * 64 + hy) * 64 + wx];
                int ka = c * 9 + kh * 3 + kw;
                acc += W[(o * 128 + c) * 9 + kh * 3 + kw] * xv;
#pragma unroll
                for (int r = 0; r < 8; ++r) hr[r] += lA[r * 1152 + ka] * xv;
            }
        }
    float ls = 0.f;
#pragma unroll
    for (int r = 0; r < 8; ++r) ls += lB[o * 8 + r] * hr[r];
    out[idx] = acc + 2.0f * ls;
}

// ---------------------------------------------------------------------------
extern "C" void kernel_launch(void* const* d_in, const int* in_sizes, int n_in,
                              void* d_out, int out_size, void* d_ws, size_t ws_size,
                              hipStream_t stream) {
    const float* x  = (const float*)d_in[0];
    const float* W  = (const float*)d_in[1];
    const float* b  = (const float*)d_in[2];
    const float* lA = (const float*)d_in[3];
    const float* lB = (const float*)d_in[4];
    float* out = (float*)d_out;

    if (ws_size < WS_NEED) {
        conv_naive<<<out_size / 256, 256, 0, stream>>>(x, W, b, lA, lB, out);
        return;
    }

    __bf16* xpad = (__bf16*)d_ws;
    __hip_bfloat16* Wt = (__hip_bfloat16*)((char*)d_ws + XPAD_BYTES);

    pad_prep<<<1024 + 128, 256, 0, stream>>>(x, xpad, W, lA, lB, Wt);
    conv_mfma<<<256, 512, 0, stream>>>(xpad, (const __bf16*)Wt, b, out);
}

// Round 7
// 135.199 us; speedup vs baseline: 1.0271x; 1.0078x over previous
//
#include <hip/hip_runtime.h>
#include <hip/hip_bf16.h>

// Conv2dWithLoRA: out = conv3x3(x, W_eff) + b, where W_eff = W + 2.0 * B@A.
// LoRA folded into weights -> single implicit-GEMM conv, bf16 MFMA, fp32 accum.
// M = 16*64*64 = 65536 pixels, N = 256 outs, K = 128*9 = 1152 (36 chunks of 32).
// R3..R8 history: FOUR structures (depth-1 dbuf / depth-3 quad / 2-phase split /
//   weights-in-VGPR) ALL land at 29-32% MfmaUtil. Schedule and LDS traffic are
//   NOT the lever. Invariant: ONE 512-thread block per CU, 8 waves lockstep on
//   one barrier -> every vmcnt/lgkm/barrier stall hits all waves at once
//   (m233: 2 waves/SIMD reach 86% peak MFMA-only, so issue isn't the limit).
// R9 (this round): BREAK THE CONVOY BY OCCUPANCY.
//   - 128pix x 256o tile, 256 thr / 4 waves, 32 KB LDS -> 512 blocks =
//     2 INDEPENDENT blocks per CU. Same 2 waves/SIMD, but from different
//     blocks with independent barriers -> stalls decorrelate (m114/m97: this
//     implicit wave-level overlap is how m97 hit 874-912 TF with a plain loop).
//   - per-wave structure BIT-IDENTICAL to R8 (64pix x 128o per wave, 32 MFMA,
//     8 weight gloads depth-1, 2 stage instrs depth-2, vmcnt(2)/chunk).

#define CIN   128
#define COUT  256
#define NBAT  16
#define HPAD  66
#define WPAD  66

typedef __bf16 bf16x8 __attribute__((ext_vector_type(8)));
typedef float f32x4 __attribute__((ext_vector_type(4)));

#define XPAD_ELEMS ((size_t)NBAT * HPAD * WPAD * CIN)   // 8,921,088
#define XPAD_BYTES (XPAD_ELEMS * 2)                      // 17,842,176
#define WT_ELEMS   ((size_t)9 * COUT * CIN)              // 294,912
#define WS_NEED    (XPAD_BYTES + WT_ELEMS * 2)

typedef __attribute__((address_space(1))) void gvoid;
typedef __attribute__((address_space(3))) void lvoid;

__device__ __forceinline__ void load_lds16(const void* g, void* l) {
    // async global->LDS, 16B per lane; LDS dest = wave-uniform base + lane*16
    __builtin_amdgcn_global_load_lds((gvoid*)g, (lvoid*)l, 16, 0, 0);
}

// ---------------------------------------------------------------------------
// Fused pre-kernel: blocks [0,1024) = pad_x, blocks [1024,1152) = prep_w.
// prep_w writes the FRAGMENT-CONTIGUOUS weight layout:
//   Wt[(((tap*4 + cb)*16 + otile)*64 + lane)*8 + j]
//   where o = otile*16 + (lane&15), c = cb*32 + (lane>>4)*8 + j.
// A conv wave then loads fragment (tap,cb,otile) as one contiguous 1KB
// global_load_dwordx4 (lane l -> base + l*16B), no LDS, no swizzle.
__global__ void pad_prep(const float* __restrict__ x, __bf16* __restrict__ xpad,
                         const float* __restrict__ W, const float* __restrict__ lA,
                         const float* __restrict__ lB, __hip_bfloat16* __restrict__ Wt) {
    __shared__ float tile[128][66];
    const int t = threadIdx.x;

    if (blockIdx.x >= 1024) {
        // ---- prep_w: 128 blocks, each thread owns one (o,c), loops 9 taps
        const int idx = (blockIdx.x - 1024) * 256 + t;   // o*128 + c
        const int c = idx & 127;
        const int o = idx >> 7;
        const int fr    = o & 15;
        const int otile = o >> 4;
        const int cb    = c >> 5;
        const int kc    = (c >> 3) & 3;
        const int j     = c & 7;
        const int lane  = kc * 16 + fr;
        float lb[8];
#pragma unroll
        for (int r = 0; r < 8; ++r) lb[r] = lB[o * 8 + r];
#pragma unroll
        for (int tap = 0; tap < 9; ++tap) {
            float acc = W[(o * 128 + c) * 9 + tap];
            float s = 0.f;
#pragma unroll
            for (int r = 0; r < 8; ++r)
                s += lb[r] * lA[r * 1152 + c * 9 + tap];
            const size_t widx = (((size_t)(tap * 4 + cb) * 16 + otile) * 64 + lane) * 8 + j;
            Wt[widx] = __float2bfloat16(acc + 2.0f * s);
        }
        return;
    }

    // ---- pad_x: NCHW fp32 -> NHWC bf16 with +1 zero halo
    const int n = blockIdx.x >> 6;
    const int h = blockIdx.x & 63;
    const float* src = x + (size_t)n * 128 * 4096 + (size_t)h * 64;
#pragma unroll
    for (int i = 0; i < 8; ++i) {                      // 2048 float4 total
        int g  = i * 256 + t;
        int c  = g >> 4;
        int w4 = (g & 15) * 4;
        const float4 v = *reinterpret_cast<const float4*>(src + (size_t)c * 4096 + w4);
        const int wb = w4 ^ (((c >> 3) & 7) << 2);     // swizzle (bits 2..4)
        tile[c][wb + 0] = v.x; tile[c][wb + 1] = v.y;
        tile[c][wb + 2] = v.z; tile[c][wb + 3] = v.w;
    }
    __syncthreads();
    __bf16* dst = xpad + ((size_t)(n * 66 + h + 1) * 66 + 1) * 128;
#pragma unroll
    for (int i = 0; i < 4; ++i) {                      // 64w x 128c bf16 = 16KB
        int g  = i * 256 + t;
        int w  = g >> 4;
        int c0 = (g & 15) * 8;
        const int swr = ((c0 >> 3) & 7) << 2;          // (c0+j)>>3 == c0>>3, j<8
        bf16x8 v;
#pragma unroll
        for (int j = 0; j < 8; ++j) v[j] = (__bf16)tile[c0 + j][w ^ swr];
        *reinterpret_cast<bf16x8*>(dst + (size_t)w * 128 + c0) = v;
    }
    // halo: left/right pixel of this padded row
    bf16x8 z = {};
    __bf16* rowbase = xpad + (size_t)(n * 66 + h + 1) * 66 * 128;
    if (t < 32) {
        int ww = (t < 16) ? 0 : 65;
        int c0 = (t & 15) * 8;
        *reinterpret_cast<bf16x8*>(rowbase + (size_t)ww * 128 + c0) = z;
    }
    // top/bottom halo rows (full 66 px)
    if (h == 0 || h == 63) {
        __bf16* hrow = xpad + (size_t)(n * 66 + (h == 0 ? 0 : 65)) * 66 * 128;
        for (int i = t; i < 66 * 16; i += 256)
            *reinterpret_cast<bf16x8*>(hrow + (size_t)i * 8) = z;
    }
}

// ---------------------------------------------------------------------------
// Main kernel. Tile 128(pix) x 256(o), BK=32, 4 waves (2 pix-halves x 2
// o-halves), per-wave output 64 pix x 128 o. 512 blocks -> 2 blocks/CU.
// LDS: B (pixels) only, 4 buffers x 8KB = 32 KB, buf = chunk&3.
// Weights: depth-1 prefetch into named reg sets wA/wB (8 x f32x4 each).
// Swizzle (B only, 64B rows): slot = c ^ ((r>>1)&3); inverse pre-applied on
// the per-lane GLOBAL address, LDS dest linear (rule #21).
// vmcnt accounting per BODY(t): at top, outstanding = sB(t)[2,maybe retired]
// + w(t)[8] + sB(t+1)[2]; vmcnt(2) retires sB(t)+w(t), leaves sB(t+1) in
// flight. Then issue w(t+1)[8] + sB(t+2)[2]. Tail t=34: w35 only; t=35:
// vmcnt(0) drains.
__global__ void __launch_bounds__(256, 2) conv_mfma(
    const __bf16* __restrict__ xpad, const __bf16* __restrict__ Wt,
    const float* __restrict__ bias, float* __restrict__ out) {
    __shared__ __align__(16) __bf16 lds[16384];        // 32 KiB

    const int tid  = threadIdx.x;
    const int wv   = tid >> 6;                         // 0..3
    const int lane = tid & 63;

    const int n  = blockIdx.x >> 5;                    // 32 tiles per image
    const int h0 = (blockIdx.x & 31) << 1;             // 2 output rows per tile

    // ---- B staging addresses (pixels) --------------------------------------
    // Wave wv stages pixel rows [wv*32, wv*32+32) as 2 instrs of 16 rows.
    const int lrow = lane >> 2;                                    // 0..15
    const int lswz = (((lane & 3) ^ ((lane >> 3) & 3)) << 3);      // elems
    const __bf16* bG[2];
#pragma unroll
    for (int j = 0; j < 2; ++j) {
        const int r0 = wv * 32 + j * 16;               // first pixel row, mult 16
        // pixel p = r0 + lrow; p>>6 constant within instr; (r0&63)+lrow <= 63
        bG[j] = xpad + (((size_t)(n * 66 + h0 + (r0 >> 6)) * 66 + (r0 & 63) + lrow) * 128) + lswz;
    }

    // ---- per-wave geometry --------------------------------------------------
    const int wo   = (wv >> 1) << 7;                   // o offset: 0 / 128
    const int wot  = (wv >> 1) << 3;                   // o-tile base: 0 / 8
    const int wpix = (wv & 1) << 6;                    // pix offset: 0 / 64
    const int fr   = lane & 15;
    const int fphys = (((lane >> 4) ^ ((lane >> 1) & 3)) << 3);
    const int b_rd = (wpix + fr) * 32 + fphys;         // + pi*512 + buf

    // weight fragment base: lane-contiguous layout
    const __bf16* wG = Wt + (size_t)wot * 512 + lane * 8;

    f32x4 acc[4][8] = {};                              // [pix tile][o tile]
    f32x4 wA[8], wB[8];                                // weight frags (named!)

#define WL(dst, ptr, imm)                                                      \
    asm volatile("global_load_dwordx4 %0, %1, off offset:" #imm                \
                 : "=&v"(dst) : "v"(ptr) : "memory")

#define WLOADS(WN, u) do {                                                     \
        const __bf16* wp0_ = wG + (size_t)(u) * 8192;                          \
        const __bf16* wp1_ = wp0_ + 2048;                                      \
        WL(WN[0], wp0_, 0);    WL(WN[1], wp0_, 1024);                          \
        WL(WN[2], wp0_, 2048); WL(WN[3], wp0_, 3072);                          \
        WL(WN[4], wp1_, 0);    WL(WN[5], wp1_, 1024);                          \
        WL(WN[6], wp1_, 2048); WL(WN[7], wp1_, 3072);                          \
    } while (0)

#define STAGE(u) do {                                                          \
        const int u_ = (u);                                                    \
        const int tap_ = u_ >> 2, cb_ = u_ & 3;                                \
        const int kh_ = (tap_ >= 6) ? 2 : (tap_ >= 3 ? 1 : 0);                 \
        const int kw_ = tap_ - kh_ * 3;                                        \
        const int bo_ = (kh_ * 66 + kw_) * 128 + cb_ * 32;                     \
        const int lb_ = (u_ & 3) * 4096;                                       \
        load_lds16(bG[0] + bo_, lds + lb_ + (wv * 32) * 32);                   \
        load_lds16(bG[1] + bo_, lds + lb_ + (wv * 32 + 16) * 32);              \
    } while (0)

#define COMPUTE(t_, WC) do {                                                   \
        const __bf16* Bb = lds + ((t_) & 3) * 4096 + b_rd;                     \
        bf16x8 bfr[4];                                                         \
        _Pragma("unroll")                                                      \
        for (int pi = 0; pi < 4; ++pi)                                         \
            bfr[pi] = *reinterpret_cast<const bf16x8*>(Bb + pi * 512);         \
        __builtin_amdgcn_s_setprio(1);                                         \
        _Pragma("unroll")                                                      \
        for (int pi = 0; pi < 4; ++pi)                                         \
            _Pragma("unroll")                                                  \
            for (int oi = 0; oi < 8; ++oi)                                     \
                acc[pi][oi] = __builtin_amdgcn_mfma_f32_16x16x32_bf16(         \
                    bfr[pi], __builtin_bit_cast(bf16x8, WC[oi]),               \
                    acc[pi][oi], 0, 0, 0);                                     \
        __builtin_amdgcn_s_setprio(0);                                         \
    } while (0)

#define BODY(t_, WC, WN) do {                                                  \
        asm volatile("s_waitcnt vmcnt(2)" ::: "memory");                       \
        __builtin_amdgcn_sched_barrier(0);                                     \
        __builtin_amdgcn_s_barrier();                                          \
        __builtin_amdgcn_sched_barrier(0);                                     \
        WLOADS(WN, (t_) + 1);                                                  \
        __builtin_amdgcn_sched_barrier(0);                                     \
        STAGE((t_) + 2);                                                       \
        __builtin_amdgcn_sched_barrier(0);                                     \
        COMPUTE(t_, WC);                                                       \
    } while (0)

    // prologue: w0 -> wA, then stage chunks 0,1 (issue order matters: vmcnt
    // counting assumes [w0(8), sB0(2), sB1(2)] = 12 outstanding).
    WLOADS(wA, 0);
    __builtin_amdgcn_sched_barrier(0);
    STAGE(0);
    STAGE(1);
    __builtin_amdgcn_sched_barrier(0);

    for (int tt = 0; tt < 17; ++tt) {                  // chunks 0..33
        BODY(2 * tt,     wA, wB);
        BODY(2 * tt + 1, wB, wA);
    }
    // t = 34: issue w35 only (no stage 36)
    asm volatile("s_waitcnt vmcnt(2)" ::: "memory");
    __builtin_amdgcn_sched_barrier(0);
    __builtin_amdgcn_s_barrier();
    __builtin_amdgcn_sched_barrier(0);
    WLOADS(wB, 35);
    __builtin_amdgcn_sched_barrier(0);
    COMPUTE(34, wA);
    // t = 35: drain everything (sB35 + w35)
    asm volatile("s_waitcnt vmcnt(0)" ::: "memory");
    __builtin_amdgcn_sched_barrier(0);
    __builtin_amdgcn_s_barrier();
    __builtin_amdgcn_sched_barrier(0);
    COMPUTE(35, wB);

#undef BODY
#undef COMPUTE
#undef STAGE
#undef WLOADS
#undef WL

    // epilogue (swapped D): row=(lane>>4)*4+j = pixel, col=lane&15 = o.
    // Lane's 4 acc components = 4 consecutive w -> dwordx4 stores.
    const int col = lane & 15;
    const int q4  = (lane >> 4) << 2;                  // pixel sub-offset
    const int h   = h0 + (wpix >> 6);                  // wpix in {0,64}
    float bo[8];
#pragma unroll
    for (int oi = 0; oi < 8; ++oi) bo[oi] = bias[wo + oi * 16 + col];
#pragma unroll
    for (int pi = 0; pi < 4; ++pi) {
        const int w0 = pi * 16 + q4;                   // 0..63
#pragma unroll
        for (int oi = 0; oi < 8; ++oi) {
            const int o = wo + oi * 16 + col;
            f32x4 v;
#pragma unroll
            for (int j = 0; j < 4; ++j) v[j] = acc[pi][oi][j] + bo[oi];
            *reinterpret_cast<f32x4*>(out + (((size_t)n * 256 + o) * 64 + h) * 64 + w0) = v;
        }
    }
}

// ---------------------------------------------------------------------------
// Fallback (only if workspace too small): naive fp32, correct but slow.
__global__ void conv_naive(const float* __restrict__ x, const float* __restrict__ W,
                           const float* __restrict__ b, const float* __restrict__ lA,
                           const float* __restrict__ lB, float* __restrict__ out) {
    int idx = blockIdx.x * 256 + threadIdx.x;          // ((n*256+o)*64+h)*64+w
    int w = idx & 63, h = (idx >> 6) & 63, o = (idx >> 12) & 255, n = idx >> 20;
    float acc = b[o];
    float hr[8] = {0, 0, 0, 0, 0, 0, 0, 0};
    for (int c = 0; c < 128; ++c)
        for (int kh = 0; kh < 3; ++kh) {
            int hy = h + kh - 1;
            if (hy < 0 || hy > 63) continue;
            for (int kw = 0; kw < 3; ++kw) {
                int wx = w + kw - 1;
                if (wx < 0 || wx > 63) continue;
                float xv = x[((n * 128 + c) * 64 + hy) * 64 + wx];
                int ka = c * 9 + kh * 3 + kw;
                acc += W[(o * 128 + c) * 9 + kh * 3 + kw] * xv;
#pragma unroll
                for (int r = 0; r < 8; ++r) hr[r] += lA[r * 1152 + ka] * xv;
            }
        }
    float ls = 0.f;
#pragma unroll
    for (int r = 0; r < 8; ++r) ls += lB[o * 8 + r] * hr[r];
    out[idx] = acc + 2.0f * ls;
}

// ---------------------------------------------------------------------------
extern "C" void kernel_launch(void* const* d_in, const int* in_sizes, int n_in,
                              void* d_out, int out_size, void* d_ws, size_t ws_size,
                              hipStream_t stream) {
    const float* x  = (const float*)d_in[0];
    const float* W  = (const float*)d_in[1];
    const float* b  = (const float*)d_in[2];
    const float* lA = (const float*)d_in[3];
    const float* lB = (const float*)d_in[4];
    float* out = (float*)d_out;

    if (ws_size < WS_NEED) {
        conv_naive<<<out_size / 256, 256, 0, stream>>>(x, W, b, lA, lB, out);
        return;
    }

    __bf16* xpad = (__bf16*)d_ws;
    __hip_bfloat16* Wt = (__hip_bfloat16*)((char*)d_ws + XPAD_BYTES);

    pad_prep<<<1024 + 128, 256, 0, stream>>>(x, xpad, W, lA, lB, Wt);
    conv_mfma<<<512, 256, 0, stream>>>(xpad, (const __bf16*)Wt, b, out);
}